// Round 9
// baseline (4961.319 us; speedup 1.0000x reference)
//
#include <hip/hip_runtime.h>

// GLAT: B=64, N=256, D=1024, H=8, DK=64, DI=2048.
// I/O dtype: float32. Internal: bf16 MFMA + f32 accum. adj/slf: int32.

typedef unsigned short u16;
typedef unsigned long long u64;
typedef __bf16 bf16_t;
typedef bf16_t bf16x8 __attribute__((ext_vector_type(8)));
typedef float  f32x4  __attribute__((ext_vector_type(4)));
typedef u16    u16x8  __attribute__((ext_vector_type(8)));
typedef u16    u16x4  __attribute__((ext_vector_type(4)));

__device__ __forceinline__ float bf2f(u16 u){
  union { unsigned int i; float f; } c; c.i = ((unsigned int)u) << 16; return c.f;
}
__device__ __forceinline__ u16 f2bf(float f){
  union { float f; unsigned int u; } c; c.f = f;
  unsigned int u = c.u;
  unsigned int r = (u + 0x7fffu + ((u >> 16) & 1u)) >> 16;  // RNE
  return (u16)r;
}

// async 16B global -> LDS (direct). LDS dest = wave-uniform base + lane*16.
__device__ __forceinline__ void gl16(const u16* g, u16* l){
  __builtin_amdgcn_global_load_lds(
      (const __attribute__((address_space(1))) void*)g,
      (__attribute__((address_space(3))) void*)l, 16, 0, 0);
}

// ---------------- diagnostic fallback: zero d_out (f32) ----------------------
__global__ __launch_bounds__(256) void zero_out(float* out, int n){
  for (int i = blockIdx.x * 256 + threadIdx.x; i < n; i += 256 * 4096) out[i] = 0.f;
}

// ---------------- f32 -> bf16 bulk convert (8 elems/thread) ------------------
__global__ __launch_bounds__(256) void cvt_bf16(
    const float* __restrict__ in, u16* __restrict__ out)
{
  const size_t i = ((size_t)blockIdx.x * 256 + threadIdx.x) * 8;
  f32x4 a = *(const f32x4*)&in[i];
  f32x4 b = *(const f32x4*)&in[i + 4];
  u16x8 o;
  #pragma unroll
  for (int j = 0; j < 4; ++j){ o[j] = f2bf(a[j]); o[4+j] = f2bf(b[j]); }
  *(u16x8*)&out[i] = o;
}

// -------- weight transpose+convert: src f32 [K][N] -> dst bf16 [(off+n)*K+k] --
__global__ __launch_bounds__(256) void transpose_w(
    const float* __restrict__ src, u16* __restrict__ dst, int K, int N, int dstOff)
{
  __shared__ u16 tile[32][33];
  const int bk = blockIdx.x * 32, bn = blockIdx.y * 32;
  const int t = threadIdx.x;
  const int r = t >> 5, c = t & 31;
  #pragma unroll
  for (int p = 0; p < 4; ++p)
    tile[r + p*8][c] = f2bf(src[(size_t)(bk + r + p*8) * N + bn + c]);
  __syncthreads();
  #pragma unroll
  for (int p = 0; p < 4; ++p)
    dst[(size_t)(dstOff + bn + r + p*8) * K + bk + c] = tile[c][r + p*8];
}

// ---- GEMM 256x256, BK=32, 8 waves, DOUBLE-buffered LDS, counted vmcnt ------
// C = A[M,K] @ BT[N,:]^T. A split at ksplit between A0/A1 (row stride Astride).
// BT row stride = Bld. ACC: out += result (pass bias=null).
// LDS[row][c16] holds global slot (c16 ^ ((row>>1)&3)); gl16 dest linear.
// 64 KB LDS -> 2 blocks/CU (4 waves/SIMD): wave-level overlap feeds MFMA.
template<int RELU, int OF32, int ACC>
__global__ __launch_bounds__(512, 4) void gemm256(
    const u16* __restrict__ A0, const u16* __restrict__ A1,
    int Astride, int ksplit,
    const u16* __restrict__ BT, int Bld, int M, int N, int K,
    const float* __restrict__ bias, void* __restrict__ outv, int out_ld)
{
  __shared__ u16 lds[2*16384];           // 2 x (A 8192 el | B 8192 el)
  const int tid  = threadIdx.x;
  const int lane = tid & 63;
  const int wid  = tid >> 6;             // 0..7
  const int wm = wid >> 2, wn = wid & 3; // 2M x 4N waves
  const int l15 = lane & 15, l4 = lane >> 4;
  const int m0 = blockIdx.x * 256, n0 = blockIdx.y * 256;

  f32x4 acc[8][4];
  #pragma unroll
  for (int i = 0; i < 8; ++i)
    #pragma unroll
    for (int j = 0; j < 4; ++j)
      acc[i][j] = (f32x4){0.f, 0.f, 0.f, 0.f};

  // per-thread staging geometry (invariant across tiles)
  const int sA0 = tid,        sA1 = tid + 512;  // slot = row*4 + c16
  const int rA0 = sA0 >> 2,   cA0 = sA0 & 3;
  const int rA1 = sA1 >> 2,   cA1 = sA1 & 3;
  const int gA0 = cA0 ^ ((rA0 >> 1) & 3), gA1 = cA1 ^ ((rA1 >> 1) & 3);
  const size_t aoff0 = (size_t)(m0 + rA0) * Astride + gA0*8;
  const size_t aoff1 = (size_t)(m0 + rA1) * Astride + gA1*8;
  const size_t boff0 = (size_t)(n0 + rA0) * Bld + gA0*8;
  const size_t boff1 = (size_t)(n0 + rA1) * Bld + gA1*8;

  const int nt = K >> 5;

  auto stage = [&](int kt, int buf){
    const int kb = kt * 32;
    const u16* Ab = A0; int kl = kb;
    if (kb >= ksplit){ Ab = A1; kl = kb - ksplit; }
    u16* dst = &lds[buf * 16384];
    gl16(&Ab[aoff0 + kl], &dst[sA0 * 8]);
    gl16(&Ab[aoff1 + kl], &dst[sA1 * 8]);
    gl16(&BT[boff0 + kb], &dst[8192 + sA0 * 8]);
    gl16(&BT[boff1 + kb], &dst[8192 + sA1 * 8]);
  };

  stage(0, 0);

  for (int t = 0; t < nt; ++t){
    const int bsel = t & 1;
    if (t + 1 < nt){
      stage(t + 1, bsel ^ 1);              // writes the buffer read at t-1
      asm volatile("s_waitcnt vmcnt(4)" ::: "memory");   // my L(t) landed
    } else {
      asm volatile("s_waitcnt vmcnt(0)" ::: "memory");
    }
    __builtin_amdgcn_sched_barrier(0);
    __builtin_amdgcn_s_barrier();          // all waves' L(t) landed
    __builtin_amdgcn_sched_barrier(0);

    const u16* Abuf = &lds[bsel * 16384];
    const u16* Bbuf = &lds[bsel * 16384 + 8192];
    bf16x8 bfr[4], afr[8];
    #pragma unroll
    for (int j = 0; j < 4; ++j){
      const int row = wn*64 + j*16 + l15;
      bfr[j] = *(const bf16x8*)&Bbuf[row*32 + ((l4 ^ ((row >> 1) & 3)) * 8)];
    }
    #pragma unroll
    for (int i = 0; i < 8; ++i){
      const int row = wm*128 + i*16 + l15;
      afr[i] = *(const bf16x8*)&Abuf[row*32 + ((l4 ^ ((row >> 1) & 3)) * 8)];
    }
    __builtin_amdgcn_s_setprio(1);
    #pragma unroll
    for (int i = 0; i < 8; ++i)
      #pragma unroll
      for (int j = 0; j < 4; ++j)
        acc[i][j] = __builtin_amdgcn_mfma_f32_16x16x32_bf16(afr[i], bfr[j], acc[i][j], 0, 0, 0);
    __builtin_amdgcn_s_setprio(0);
    __builtin_amdgcn_sched_barrier(0);
    __builtin_amdgcn_s_barrier();          // all reads of buf[t&1] done
    __builtin_amdgcn_sched_barrier(0);
  }

  // epilogue: C[row][col], row=(lane>>4)*4+r, col=lane&15 (m89-verified)
  const int rb = m0 + wm*128 + l4*4;
  const int cb = n0 + wn*64 + l15;
  #pragma unroll
  for (int i = 0; i < 8; ++i){
    #pragma unroll
    for (int j = 0; j < 4; ++j){
      const int col = cb + j*16;
      const float badd = bias ? bias[col] : 0.f;
      #pragma unroll
      for (int r = 0; r < 4; ++r){
        const int row = rb + i*16 + r;
        float y = acc[i][j][r] + badd;
        if (RELU) y = y > 0.f ? y : 0.f;
        if (OF32){
          float* po = &((float*)outv)[(size_t)row * out_ld + col];
          if (ACC) y += *po;
          *po = y;
        } else {
          u16* po = &((u16*)outv)[(size_t)row * out_ld + col];
          if (ACC) y += bf2f(*po);
          *po = f2bf(y);
        }
      }
    }
  }
}

// -------- mask pack: bit k of mb[row][c] = mask(row, c*64+k) -----------------
__global__ __launch_bounds__(256) void mask_pack(
    const int* __restrict__ slf, const int* __restrict__ adj,
    u64* __restrict__ mb_g, u64* __restrict__ mb_l)
{
  const int idx  = blockIdx.x * 4 + (threadIdx.x >> 6);  // (row, c) pair
  const int lane = threadIdx.x & 63;
  const size_t mi = (size_t)(idx >> 2) * 256 + (size_t)(idx & 3) * 64 + lane;
  const bool g = slf[mi] != 0;
  const bool l = g || (adj[mi] == 0);
  const u64 bg = __ballot(g);
  const u64 bl = __ballot(l);
  if (lane == 0){ mb_g[idx] = bg; mb_l[idx] = bl; }
}

// ---------------- MFMA flash attention ---------------------------------------
// block = (b_loc, h, qtile of 128 rows); 4 waves x 32 q-rows.
// qkv: half-local [8192][1536]; q @ h*64, k @ 512+h*64, v @ 1024+h*64.
__global__ __launch_bounds__(256) void attn_mfma(
    const u16* __restrict__ qkv, const u64* __restrict__ mb,
    int boff, u16* __restrict__ out)
{
  __shared__ u16 kbuf[64*64];     // [key][dim], swizzled col ^= (key&7)<<3
  __shared__ u16 vtbuf[64*64];    // [dim][key], swizzled col ^= (dim&7)<<3
  __shared__ u16 pbuf[4][32*64];  // per-wave P [row][key], swizzled

  const int b_loc = blockIdx.x >> 4;
  const int h     = (blockIdx.x >> 1) & 7;
  const int qt    = blockIdx.x & 1;
  const int b     = boff + b_loc;
  const int t     = threadIdx.x;
  const int w     = t >> 6, lane = t & 63;
  const int l15   = lane & 15, l4 = lane >> 4;

  bf16x8 qf[2][2];
  {
    const int rbase = b_loc*256 + qt*128 + w*32;
    #pragma unroll
    for (int i = 0; i < 2; ++i)
      #pragma unroll
      for (int kc = 0; kc < 2; ++kc)
        qf[i][kc] = *(const bf16x8*)&qkv[(size_t)(rbase + i*16 + l15)*1536 + h*64 + kc*32 + l4*8];
  }

  f32x4 acc_o[2][4];
  float m_[2][4], l_[2][4];
  #pragma unroll
  for (int i = 0; i < 2; ++i){
    #pragma unroll
    for (int j = 0; j < 4; ++j) acc_o[i][j] = (f32x4){0.f,0.f,0.f,0.f};
    #pragma unroll
    for (int r = 0; r < 4; ++r){ m_[i][r] = -1e30f; l_[i][r] = 0.f; }
  }

  for (int c = 0; c < 4; ++c){
    __syncthreads();
    {   // stage K and V^T (swizzled); thread -> key row t>>2, dim group (t&3)*16
      const int kr = t >> 2, dg = (t & 3) * 16;
      const size_t rbase = (size_t)(b_loc*256 + c*64 + kr)*1536 + h*64 + dg;
      u16x8 k0 = *(const u16x8*)&qkv[rbase + 512];
      u16x8 k1 = *(const u16x8*)&qkv[rbase + 512 + 8];
      u16x8 v0 = *(const u16x8*)&qkv[rbase + 1024];
      u16x8 v1 = *(const u16x8*)&qkv[rbase + 1024 + 8];
      const int sw = (kr & 7) << 3;
      *(u16x8*)&kbuf[kr*64 + (dg ^ sw)]       = k0;
      *(u16x8*)&kbuf[kr*64 + ((dg + 8) ^ sw)] = k1;
      #pragma unroll
      for (int e = 0; e < 8; ++e){
        const int d0 = dg + e, d1 = dg + 8 + e;
        vtbuf[d0*64 + (kr ^ ((d0 & 7) << 3))] = v0[e];
        vtbuf[d1*64 + (kr ^ ((d1 & 7) << 3))] = v1[e];
      }
    }
    __syncthreads();

    bf16x8 kfr[4][2];
    #pragma unroll
    for (int jb = 0; jb < 4; ++jb){
      const int key = jb*16 + l15;
      const int sw = (key & 7) << 3;
      #pragma unroll
      for (int kc = 0; kc < 2; ++kc)
        kfr[jb][kc] = *(const bf16x8*)&kbuf[key*64 + ((kc*32 + l4*8) ^ sw)];
    }
    f32x4 s_[2][4];
    #pragma unroll
    for (int i = 0; i < 2; ++i)
      #pragma unroll
      for (int jb = 0; jb < 4; ++jb){
        f32x4 a = (f32x4){0.f,0.f,0.f,0.f};
        a = __builtin_amdgcn_mfma_f32_16x16x32_bf16(qf[i][0], kfr[jb][0], a, 0,0,0);
        a = __builtin_amdgcn_mfma_f32_16x16x32_bf16(qf[i][1], kfr[jb][1], a, 0,0,0);
        s_[i][jb] = a;
      }

    #pragma unroll
    for (int i = 0; i < 2; ++i){
      #pragma unroll
      for (int r = 0; r < 4; ++r){
        const int prow = i*16 + l4*4 + r;
        const int qrow = qt*128 + w*32 + prow;
        const u64 bits = mb[((size_t)b*256 + qrow)*4 + c];
        float sv[4];
        #pragma unroll
        for (int jb = 0; jb < 4; ++jb){
          float xv = s_[i][jb][r] * 0.125f;
          if ((bits >> (jb*16 + l15)) & 1ull) xv = -1e9f;
          sv[jb] = xv;
        }
        float mx = fmaxf(fmaxf(sv[0], sv[1]), fmaxf(sv[2], sv[3]));
        #pragma unroll
        for (int d = 1; d < 16; d <<= 1)
          mx = fmaxf(mx, __shfl_xor(mx, d, 64));
        const float mnew = fmaxf(m_[i][r], mx);
        const float corr = __expf(m_[i][r] - mnew);
        m_[i][r] = mnew;
        float ps = 0.f;
        const int swp = (prow & 7) << 3;
        #pragma unroll
        for (int jb = 0; jb < 4; ++jb){
          const float p = __expf(sv[jb] - mnew);
          ps += p;
          pbuf[w][prow*64 + ((jb*16 + l15) ^ swp)] = f2bf(p);
        }
        #pragma unroll
        for (int d = 1; d < 16; d <<= 1)
          ps += __shfl_xor(ps, d, 64);
        l_[i][r] = l_[i][r] * corr + ps;
        #pragma unroll
        for (int j2 = 0; j2 < 4; ++j2) acc_o[i][j2][r] *= corr;
      }
    }

    bf16x8 vfr[4][2];
    #pragma unroll
    for (int j2 = 0; j2 < 4; ++j2){
      const int dim = j2*16 + l15;
      const int sw = (dim & 7) << 3;
      #pragma unroll
      for (int kc = 0; kc < 2; ++kc)
        vfr[j2][kc] = *(const bf16x8*)&vtbuf[dim*64 + ((kc*32 + l4*8) ^ sw)];
    }
    #pragma unroll
    for (int i = 0; i < 2; ++i){
      const int prow = i*16 + l15;
      const int swp = (prow & 7) << 3;
      bf16x8 pa0 = *(const bf16x8*)&pbuf[w][prow*64 + ((l4*8) ^ swp)];
      bf16x8 pa1 = *(const bf16x8*)&pbuf[w][prow*64 + ((32 + l4*8) ^ swp)];
      #pragma unroll
      for (int j2 = 0; j2 < 4; ++j2){
        acc_o[i][j2] = __builtin_amdgcn_mfma_f32_16x16x32_bf16(pa0, vfr[j2][0], acc_o[i][j2], 0,0,0);
        acc_o[i][j2] = __builtin_amdgcn_mfma_f32_16x16x32_bf16(pa1, vfr[j2][1], acc_o[i][j2], 0,0,0);
      }
    }
  }

  #pragma unroll
  for (int i = 0; i < 2; ++i){
    #pragma unroll
    for (int r = 0; r < 4; ++r){
      const int qrow = qt*128 + w*32 + i*16 + l4*4 + r;
      const float inv = 1.f / l_[i][r];
      const size_t ob = ((size_t)b*256 + qrow)*512 + h*64;
      #pragma unroll
      for (int j2 = 0; j2 < 4; ++j2)
        out[ob + j2*16 + l15] = f2bf(acc_o[i][j2][r] * inv);
    }
  }
}

// -------- fused residual + LayerNorm + npm; a bf16, res f32|bf16, out bf16 ---
template<int RF32>
__global__ __launch_bounds__(256) void ln_fused(
    const u16* a, const void* __restrict__ res,
    const float* __restrict__ sc, const float* __restrict__ bs,
    const float* __restrict__ npm, u16* out)
{
  const int row = blockIdx.x, t = threadIdx.x;
  const size_t bse = (size_t)row * 1024 + t*4;
  u16x4 av = *(const u16x4*)&a[bse];
  float rv[4];
  if (RF32){
    f32x4 q = *(const f32x4*)&((const float*)res)[bse];
    #pragma unroll
    for (int j = 0; j < 4; ++j) rv[j] = q[j];
  } else {
    u16x4 q = *(const u16x4*)&((const u16*)res)[bse];
    #pragma unroll
    for (int j = 0; j < 4; ++j) rv[j] = bf2f(q[j]);
  }
  float vv[4]; float s = 0.f, sq = 0.f;
  #pragma unroll
  for (int j = 0; j < 4; ++j){
    vv[j] = bf2f(av[j]) + rv[j];
    s += vv[j]; sq += vv[j]*vv[j];
  }
  #pragma unroll
  for (int i = 1; i < 64; i <<= 1){
    s  += __shfl_xor(s,  i, 64);
    sq += __shfl_xor(sq, i, 64);
  }
  __shared__ float red[8];
  const int wid = t >> 6, lane = t & 63;
  if (lane == 0){ red[wid] = s; red[4 + wid] = sq; }
  __syncthreads();
  s  = red[0] + red[1] + red[2] + red[3];
  sq = red[4] + red[5] + red[6] + red[7];
  const float mean = s * (1.f/1024.f);
  const float var  = sq * (1.f/1024.f) - mean*mean;
  const float rstd = rsqrtf(var + 1e-5f);
  const float nm   = npm[row];
  u16x4 ov;
  #pragma unroll
  for (int j = 0; j < 4; ++j){
    float y = (vv[j] - mean) * rstd * sc[t*4+j] + bs[t*4+j];
    ov[j] = f2bf(y * nm);
  }
  *(u16x4*)&out[bse] = ov;
}

// ---------------- launcher ---------------------------------------------------
extern "C" void kernel_launch(void* const* d_in, const int* in_sizes, int n_in,
                              void* d_out, int out_size, void* d_ws, size_t ws_size,
                              hipStream_t stream)
{
  // ws (u16 el), 112 MiB (proven):
  //  W  [0, 8388608): wqkvT|woT|w1T|w2T|fcT
  //  R1 [8388608, 25165824):  xbf (phase1) -> tmp -> xl (phase2, in-place LN)
  //  R2 [25165824, 41943040): qkvh [8192][1536] (phase1) -> ln1 (phase2)
  //  R3 [41943040, 58720256): xg  (written once, layer-0 end; nothing aliases)
  // d_out (u16): attnb0 [0,8388608) | attnb1 [8388608,16777216)
  //   phase1: mb_g/mb_l @ 16777216 | phase2: hbufA [16777216,33554432)
  const size_t NEED = 58720256ull * 2ull;
  if (ws_size < NEED){
    zero_out<<<4096, 256, 0, stream>>>((float*)d_out, out_size);
    return;
  }

  const float* x   = (const float*)d_in[0];
  const int*   adj = (const int*)d_in[1];
  const float* npm = (const float*)d_in[2];
  const int*   slf = (const int*)d_in[3];
  const float* fcw = (const float*)d_in[30];
  const float* fcb = (const float*)d_in[31];

  u16* ws    = (u16*)d_ws;
  u16* wqkvT = ws;
  u16* woT   = ws + 1572864;
  u16* w1T   = ws + 2097152;
  u16* w2T   = ws + 4194304;
  u16* fcT   = ws + 6291456;
  u16* xbf   = ws + 8388608;           // R1: [16384][1024] bf16, then tmp/xl
  u16* tmp   = ws + 8388608;
  u16* qkvh  = ws + 25165824;          // R2: [8192][1536], then ln1
  u16* ln1   = ws + 25165824;
  u16* xg    = ws + 41943040;          // R3 (exclusive)

  u16* dout16 = (u16*)d_out;
  u16* attnb0 = dout16;                // [16384][512]
  u16* attnb1 = dout16 + 8388608;      // [16384][512]
  u16* hbufA  = dout16 + 16777216;     // [16384][1024] (phase2 only)
  u64* mb_g   = (u64*)(dout16 + 16777216);   // phase1 only (hbufA window)
  u64* mb_l   = mb_g + 65536;

  cvt_bf16<<<8192, 256, 0, stream>>>(x, xbf);
  mask_pack<<<16384, 256, 0, stream>>>(slf, adj, mb_g, mb_l);
  transpose_w<<<dim3(64, 32), 256, 0, stream>>>(fcw, fcT, 2048, 1024, 0);

  // Phase 1: both layers' QKV + attention (xbf + masks live throughout)
  for (int L = 0; L < 2; ++L){
    const int bi = 4 + L*13;
    transpose_w<<<dim3(32, 16), 256, 0, stream>>>((const float*)d_in[bi+0], wqkvT, 1024, 512, 0);
    transpose_w<<<dim3(32, 16), 256, 0, stream>>>((const float*)d_in[bi+1], wqkvT, 1024, 512, 512);
    transpose_w<<<dim3(32, 16), 256, 0, stream>>>((const float*)d_in[bi+2], wqkvT, 1024, 512, 1024);
    u16* attnb = L ? attnb1 : attnb0;
    for (int hf = 0; hf < 2; ++hf){
      const u16* xh = xbf + (size_t)hf*8192*1024;
      gemm256<0,0,0><<<dim3(32, 6), 512, 0, stream>>>(
          xh, xh, 1024, 1024, wqkvT, 1024, 8192, 1536, 1024, nullptr, qkvh, 1536);
      attn_mfma<<<512, 256, 0, stream>>>(qkvh, L ? mb_l : mb_g, hf*32, attnb);
    }
  }

  // Phase 2: layer bodies (xbf/masks dead; tmp R1, ln1 R2, hbufA in d_out)
  for (int L = 0; L < 2; ++L){
    const int bi = 4 + L*13;
    const float* bo  = (const float*)d_in[bi+4];
    const float* l1s = (const float*)d_in[bi+5];
    const float* l1b = (const float*)d_in[bi+6];
    const float* b1  = (const float*)d_in[bi+8];
    const float* b2  = (const float*)d_in[bi+10];
    const float* l2s = (const float*)d_in[bi+11];
    const float* l2b = (const float*)d_in[bi+12];

    transpose_w<<<dim3(16, 32), 256, 0, stream>>>((const float*)d_in[bi+3], woT, 512, 1024, 0);
    transpose_w<<<dim3(32, 64), 256, 0, stream>>>((const float*)d_in[bi+7], w1T, 1024, 2048, 0);
    transpose_w<<<dim3(64, 32), 256, 0, stream>>>((const float*)d_in[bi+9], w2T, 2048, 1024, 0);

    const u16* attnb = L ? attnb1 : attnb0;
    // out-proj + bo -> tmp
    gemm256<0,0,0><<<dim3(64, 4), 512, 0, stream>>>(
        attnb, attnb, 512, 512, woT, 512, 16384, 1024, 512, bo, tmp, 1024);
    // ln1 = LN(tmp + x) * npm -> R2
    ln_fused<1><<<16384, 256, 0, stream>>>(tmp, x, l1s, l1b, npm, ln1);
    // FFN: two N-halves of w1 through hbufA, K-accumulated into tmp
    for (int hh = 0; hh < 2; ++hh){
      gemm256<1,0,0><<<dim3(64, 4), 512, 0, stream>>>(
          ln1, ln1, 1024, 1024, w1T + (size_t)hh*1024*1024, 1024,
          16384, 1024, 1024, b1 + hh*1024, hbufA, 1024);
      if (hh == 0)
        gemm256<0,0,0><<<dim3(64, 4), 512, 0, stream>>>(
            hbufA, hbufA, 1024, 1024, w2T, 2048, 16384, 1024, 1024, b2, tmp, 1024);
      else
        gemm256<0,0,1><<<dim3(64, 4), 512, 0, stream>>>(
            hbufA, hbufA, 1024, 1024, w2T + 1024, 2048, 16384, 1024, 1024,
            nullptr, tmp, 1024);
    }
    // xout = LN(tmp + ln1) * npm; layer0 -> xg, layer1 -> in-place (xl = tmp)
    ln_fused<0><<<16384, 256, 0, stream>>>(tmp, ln1, l2s, l2b, npm, L ? tmp : xg);
  }

  // final: [xg | xl] @ fcT + fc_b -> d_out (f32), K split at 1024
  gemm256<0,1,0><<<dim3(64, 4), 512, 0, stream>>>(
      xg, tmp, 1024, 1024, fcT, 2048, 16384, 1024, 2048, fcb, d_out, 1024);
}

// Round 10
// 805.160 us; speedup vs baseline: 6.1619x; 6.1619x over previous
//
#include <hip/hip_runtime.h>

// GLAT: B=64, N=256, D=1024, H=8, DK=64, DI=2048.
// I/O dtype: float32. Internal: bf16 MFMA + f32 accum. adj/slf: int32.

typedef unsigned short u16;
typedef unsigned long long u64;
typedef __bf16 bf16_t;
typedef bf16_t bf16x8 __attribute__((ext_vector_type(8)));
typedef float  f32x4  __attribute__((ext_vector_type(4)));
typedef u16    u16x8  __attribute__((ext_vector_type(8)));
typedef u16    u16x4  __attribute__((ext_vector_type(4)));

__device__ __forceinline__ float bf2f(u16 u){
  union { unsigned int i; float f; } c; c.i = ((unsigned int)u) << 16; return c.f;
}
__device__ __forceinline__ u16 f2bf(float f){
  union { float f; unsigned int u; } c; c.f = f;
  unsigned int u = c.u;
  unsigned int r = (u + 0x7fffu + ((u >> 16) & 1u)) >> 16;  // RNE
  return (u16)r;
}

// async 16B global -> LDS (direct). LDS dest = wave-uniform base + lane*16.
__device__ __forceinline__ void gl16(const u16* g, u16* l){
  __builtin_amdgcn_global_load_lds(
      (const __attribute__((address_space(1))) void*)g,
      (__attribute__((address_space(3))) void*)l, 16, 0, 0);
}

// ---------------- diagnostic fallback: zero d_out (f32) ----------------------
__global__ __launch_bounds__(256) void zero_out(float* out, int n){
  for (int i = blockIdx.x * 256 + threadIdx.x; i < n; i += 256 * 4096) out[i] = 0.f;
}

// ---------------- f32 -> bf16 bulk convert (8 elems/thread) ------------------
__global__ __launch_bounds__(256) void cvt_bf16(
    const float* __restrict__ in, u16* __restrict__ out)
{
  const size_t i = ((size_t)blockIdx.x * 256 + threadIdx.x) * 8;
  f32x4 a = *(const f32x4*)&in[i];
  f32x4 b = *(const f32x4*)&in[i + 4];
  u16x8 o;
  #pragma unroll
  for (int j = 0; j < 4; ++j){ o[j] = f2bf(a[j]); o[4+j] = f2bf(b[j]); }
  *(u16x8*)&out[i] = o;
}

// -------- weight transpose+convert: src f32 [K][N] -> dst bf16 [(off+n)*K+k] --
__global__ __launch_bounds__(256) void transpose_w(
    const float* __restrict__ src, u16* __restrict__ dst, int K, int N, int dstOff)
{
  __shared__ u16 tile[32][33];
  const int bk = blockIdx.x * 32, bn = blockIdx.y * 32;
  const int t = threadIdx.x;
  const int r = t >> 5, c = t & 31;
  #pragma unroll
  for (int p = 0; p < 4; ++p)
    tile[r + p*8][c] = f2bf(src[(size_t)(bk + r + p*8) * N + bn + c]);
  __syncthreads();
  #pragma unroll
  for (int p = 0; p < 4; ++p)
    dst[(size_t)(dstOff + bn + r + p*8) * K + bk + c] = tile[c][r + p*8];
}

// ---- GEMM 256x256, BK=64, 8 waves, dbuf LDS, quadrant-phase schedule -------
// C = A[M,K] @ BT[N,:]^T. A split at ksplit between A0/A1 (row stride Astride).
// BT row stride = Bld. ACC: out += result (pass bias=null).
// LDS per buf: A[256][64] @0, B[256][64] @16384 elems; slot sl of row r holds
// global chunk sl^(r&7) (zero-conflict frag reads, measured r8); gl16 linear.
// Per K-tile: 4 quadrant phases (frag reuse) + 1 stage_half per phase;
// entry wait = counted vmcnt(2), issued one full K-tile earlier (T3/T4).
template<int RELU, int OF32, int ACC>
__global__ __launch_bounds__(512, 2) void gemm256(
    const u16* __restrict__ A0, const u16* __restrict__ A1,
    int Astride, int ksplit,
    const u16* __restrict__ BT, int Bld, int M, int N, int K,
    const float* __restrict__ bias, void* __restrict__ outv, int out_ld)
{
  __shared__ u16 lds[2*32768];           // 128 KiB
  const int tid  = threadIdx.x;
  const int lane = tid & 63;
  const int wid  = tid >> 6;             // 0..7
  const int wm = wid >> 2, wn = wid & 3; // 2M x 4N waves
  const int l15 = lane & 15, l4 = lane >> 4;
  const int m0 = blockIdx.x * 256, n0 = blockIdx.y * 256;

  f32x4 acc[8][4];
  #pragma unroll
  for (int i = 0; i < 8; ++i)
    #pragma unroll
    for (int j = 0; j < 4; ++j)
      acc[i][j] = (f32x4){0.f, 0.f, 0.f, 0.f};

  // staging: half-tile = 128 rows x 8 slots = 1024 slots; thread -> s0, s1
  const int s0 = tid, s1 = tid + 512;
  const int r0 = s0 >> 3, g0 = (s0 & 7) ^ (r0 & 7);
  const int r1 = s1 >> 3, g1 = (s1 & 7) ^ (r1 & 7);

  const int nt = K >> 6;

  auto stageA = [&](int kt, int h, int buf){
    const int kb = kt * 64;
    const u16* Ab = A0; int kl = kb;
    if (kb >= ksplit){ Ab = A1; kl = kb - ksplit; }
    u16* dst = &lds[buf*32768 + h*8192];
    gl16(&Ab[(size_t)(m0 + h*128 + r0) * Astride + kl + g0*8], &dst[s0*8]);
    gl16(&Ab[(size_t)(m0 + h*128 + r1) * Astride + kl + g1*8], &dst[s1*8]);
  };
  auto stageB = [&](int kt, int h, int buf){
    const int kb = kt * 64;
    u16* dst = &lds[buf*32768 + 16384 + h*8192];
    gl16(&BT[(size_t)(n0 + h*128 + r0) * Bld + kb + g0*8], &dst[s0*8]);
    gl16(&BT[(size_t)(n0 + h*128 + r1) * Bld + kb + g1*8], &dst[s1*8]);
  };
  auto lda = [&](int i, int kc, int buf) -> bf16x8 {
    const int r = wm*128 + i*16 + l15;
    const int c = (kc*4 + l4) ^ (r & 7);
    return *(const bf16x8*)&lds[buf*32768 + r*64 + c*8];
  };
  auto ldb = [&](int j, int kc, int buf) -> bf16x8 {
    const int r = wn*64 + j*16 + l15;
    const int c = (kc*4 + l4) ^ (r & 7);
    return *(const bf16x8*)&lds[buf*32768 + 16384 + r*64 + c*8];
  };

  // prologue: stage tile 0 fully (8 loads)
  stageA(0, 0, 0); stageA(0, 1, 0); stageB(0, 0, 0); stageB(0, 1, 0);

  for (int t = 0; t < nt; ++t){
    const int buf = t & 1, nbuf = buf ^ 1;
    const bool pf = (t + 1 < nt);
    if (pf){
      stageA(t+1, 0, nbuf);
      asm volatile("s_waitcnt vmcnt(2)" ::: "memory");  // tile t's 8 landed
    } else {
      asm volatile("s_waitcnt vmcnt(0)" ::: "memory");
    }
    __builtin_amdgcn_sched_barrier(0);
    __builtin_amdgcn_s_barrier();          // all waves' tile-t loads landed
    __builtin_amdgcn_sched_barrier(0);

    bf16x8 a_[4][2], b_[2][2];
    // ---- Q0: A-lo x B-lo (12 ds_reads, 16 MFMA) ----
    #pragma unroll
    for (int i = 0; i < 4; ++i){ a_[i][0] = lda(i, 0, buf); a_[i][1] = lda(i, 1, buf); }
    #pragma unroll
    for (int j = 0; j < 2; ++j){ b_[j][0] = ldb(j, 0, buf); b_[j][1] = ldb(j, 1, buf); }
    if (pf) stageA(t+1, 1, nbuf);
    __builtin_amdgcn_s_setprio(1);
    #pragma unroll
    for (int i = 0; i < 4; ++i)
      #pragma unroll
      for (int j = 0; j < 2; ++j){
        acc[i][j] = __builtin_amdgcn_mfma_f32_16x16x32_bf16(a_[i][0], b_[j][0], acc[i][j], 0,0,0);
        acc[i][j] = __builtin_amdgcn_mfma_f32_16x16x32_bf16(a_[i][1], b_[j][1], acc[i][j], 0,0,0);
      }
    __builtin_amdgcn_s_setprio(0);
    // ---- Q1: A-lo x B-hi (4 ds_reads, 16 MFMA) ----
    #pragma unroll
    for (int j = 0; j < 2; ++j){ b_[j][0] = ldb(2+j, 0, buf); b_[j][1] = ldb(2+j, 1, buf); }
    if (pf) stageB(t+1, 0, nbuf);
    __builtin_amdgcn_s_setprio(1);
    #pragma unroll
    for (int i = 0; i < 4; ++i)
      #pragma unroll
      for (int j = 0; j < 2; ++j){
        acc[i][2+j] = __builtin_amdgcn_mfma_f32_16x16x32_bf16(a_[i][0], b_[j][0], acc[i][2+j], 0,0,0);
        acc[i][2+j] = __builtin_amdgcn_mfma_f32_16x16x32_bf16(a_[i][1], b_[j][1], acc[i][2+j], 0,0,0);
      }
    __builtin_amdgcn_s_setprio(0);
    // ---- Q2: A-hi x B-hi (8 ds_reads, 16 MFMA) ----
    #pragma unroll
    for (int i = 0; i < 4; ++i){ a_[i][0] = lda(4+i, 0, buf); a_[i][1] = lda(4+i, 1, buf); }
    if (pf) stageB(t+1, 1, nbuf);
    __builtin_amdgcn_s_setprio(1);
    #pragma unroll
    for (int i = 0; i < 4; ++i)
      #pragma unroll
      for (int j = 0; j < 2; ++j){
        acc[4+i][2+j] = __builtin_amdgcn_mfma_f32_16x16x32_bf16(a_[i][0], b_[j][0], acc[4+i][2+j], 0,0,0);
        acc[4+i][2+j] = __builtin_amdgcn_mfma_f32_16x16x32_bf16(a_[i][1], b_[j][1], acc[4+i][2+j], 0,0,0);
      }
    __builtin_amdgcn_s_setprio(0);
    // ---- Q3: A-hi x B-lo (4 ds_reads, 16 MFMA) ----
    #pragma unroll
    for (int j = 0; j < 2; ++j){ b_[j][0] = ldb(j, 0, buf); b_[j][1] = ldb(j, 1, buf); }
    __builtin_amdgcn_s_setprio(1);
    #pragma unroll
    for (int i = 0; i < 4; ++i)
      #pragma unroll
      for (int j = 0; j < 2; ++j){
        acc[4+i][j] = __builtin_amdgcn_mfma_f32_16x16x32_bf16(a_[i][0], b_[j][0], acc[4+i][j], 0,0,0);
        acc[4+i][j] = __builtin_amdgcn_mfma_f32_16x16x32_bf16(a_[i][1], b_[j][1], acc[4+i][j], 0,0,0);
      }
    __builtin_amdgcn_s_setprio(0);

    __builtin_amdgcn_sched_barrier(0);
    __builtin_amdgcn_s_barrier();          // all reads of buf done
    __builtin_amdgcn_sched_barrier(0);
  }

  // epilogue: C[row][col], row=(lane>>4)*4+r, col=lane&15 (m89-verified)
  const int rb = m0 + wm*128 + l4*4;
  const int cb = n0 + wn*64 + l15;
  #pragma unroll
  for (int i = 0; i < 8; ++i){
    #pragma unroll
    for (int j = 0; j < 4; ++j){
      const int col = cb + j*16;
      const float badd = bias ? bias[col] : 0.f;
      #pragma unroll
      for (int r = 0; r < 4; ++r){
        const int row = rb + i*16 + r;
        float y = acc[i][j][r] + badd;
        if (RELU) y = y > 0.f ? y : 0.f;
        if (OF32){
          float* po = &((float*)outv)[(size_t)row * out_ld + col];
          if (ACC) y += *po;
          *po = y;
        } else {
          u16* po = &((u16*)outv)[(size_t)row * out_ld + col];
          if (ACC) y += bf2f(*po);
          *po = f2bf(y);
        }
      }
    }
  }
}

// -------- mask pack: bit k of mb[row][c] = mask(row, c*64+k) -----------------
__global__ __launch_bounds__(256) void mask_pack(
    const int* __restrict__ slf, const int* __restrict__ adj,
    u64* __restrict__ mb_g, u64* __restrict__ mb_l)
{
  const int idx  = blockIdx.x * 4 + (threadIdx.x >> 6);  // (row, c) pair
  const int lane = threadIdx.x & 63;
  const size_t mi = (size_t)(idx >> 2) * 256 + (size_t)(idx & 3) * 64 + lane;
  const bool g = slf[mi] != 0;
  const bool l = g || (adj[mi] == 0);
  const u64 bg = __ballot(g);
  const u64 bl = __ballot(l);
  if (lane == 0){ mb_g[idx] = bg; mb_l[idx] = bl; }
}

// ---------------- MFMA flash attention ---------------------------------------
// block = (b_loc, h, qtile of 128 rows); 4 waves x 32 q-rows.
// qkv: half-local [8192][1536]; q @ h*64, k @ 512+h*64, v @ 1024+h*64.
__global__ __launch_bounds__(256) void attn_mfma(
    const u16* __restrict__ qkv, const u64* __restrict__ mb,
    int boff, u16* __restrict__ out)
{
  __shared__ u16 kbuf[64*64];     // [key][dim], swizzled col ^= (key&7)<<3
  __shared__ u16 vtbuf[64*64];    // [dim][key], swizzled col ^= (dim&7)<<3
  __shared__ u16 pbuf[4][32*64];  // per-wave P [row][key], swizzled

  const int b_loc = blockIdx.x >> 4;
  const int h     = (blockIdx.x >> 1) & 7;
  const int qt    = blockIdx.x & 1;
  const int b     = boff + b_loc;
  const int t     = threadIdx.x;
  const int w     = t >> 6, lane = t & 63;
  const int l15   = lane & 15, l4 = lane >> 4;

  bf16x8 qf[2][2];
  {
    const int rbase = b_loc*256 + qt*128 + w*32;
    #pragma unroll
    for (int i = 0; i < 2; ++i)
      #pragma unroll
      for (int kc = 0; kc < 2; ++kc)
        qf[i][kc] = *(const bf16x8*)&qkv[(size_t)(rbase + i*16 + l15)*1536 + h*64 + kc*32 + l4*8];
  }

  f32x4 acc_o[2][4];
  float m_[2][4], l_[2][4];
  #pragma unroll
  for (int i = 0; i < 2; ++i){
    #pragma unroll
    for (int j = 0; j < 4; ++j) acc_o[i][j] = (f32x4){0.f,0.f,0.f,0.f};
    #pragma unroll
    for (int r = 0; r < 4; ++r){ m_[i][r] = -1e30f; l_[i][r] = 0.f; }
  }

  for (int c = 0; c < 4; ++c){
    __syncthreads();
    {   // stage K and V^T (swizzled); thread -> key row t>>2, dim group (t&3)*16
      const int kr = t >> 2, dg = (t & 3) * 16;
      const size_t rbase = (size_t)(b_loc*256 + c*64 + kr)*1536 + h*64 + dg;
      u16x8 k0 = *(const u16x8*)&qkv[rbase + 512];
      u16x8 k1 = *(const u16x8*)&qkv[rbase + 512 + 8];
      u16x8 v0 = *(const u16x8*)&qkv[rbase + 1024];
      u16x8 v1 = *(const u16x8*)&qkv[rbase + 1024 + 8];
      const int sw = (kr & 7) << 3;
      *(u16x8*)&kbuf[kr*64 + (dg ^ sw)]       = k0;
      *(u16x8*)&kbuf[kr*64 + ((dg + 8) ^ sw)] = k1;
      #pragma unroll
      for (int e = 0; e < 8; ++e){
        const int d0 = dg + e, d1 = dg + 8 + e;
        vtbuf[d0*64 + (kr ^ ((d0 & 7) << 3))] = v0[e];
        vtbuf[d1*64 + (kr ^ ((d1 & 7) << 3))] = v1[e];
      }
    }
    __syncthreads();

    bf16x8 kfr[4][2];
    #pragma unroll
    for (int jb = 0; jb < 4; ++jb){
      const int key = jb*16 + l15;
      const int sw = (key & 7) << 3;
      #pragma unroll
      for (int kc = 0; kc < 2; ++kc)
        kfr[jb][kc] = *(const bf16x8*)&kbuf[key*64 + ((kc*32 + l4*8) ^ sw)];
    }
    f32x4 s_[2][4];
    #pragma unroll
    for (int i = 0; i < 2; ++i)
      #pragma unroll
      for (int jb = 0; jb < 4; ++jb){
        f32x4 a = (f32x4){0.f,0.f,0.f,0.f};
        a = __builtin_amdgcn_mfma_f32_16x16x32_bf16(qf[i][0], kfr[jb][0], a, 0,0,0);
        a = __builtin_amdgcn_mfma_f32_16x16x32_bf16(qf[i][1], kfr[jb][1], a, 0,0,0);
        s_[i][jb] = a;
      }

    #pragma unroll
    for (int i = 0; i < 2; ++i){
      #pragma unroll
      for (int r = 0; r < 4; ++r){
        const int prow = i*16 + l4*4 + r;
        const int qrow = qt*128 + w*32 + prow;
        const u64 bits = mb[((size_t)b*256 + qrow)*4 + c];
        float sv[4];
        #pragma unroll
        for (int jb = 0; jb < 4; ++jb){
          float xv = s_[i][jb][r] * 0.125f;
          if ((bits >> (jb*16 + l15)) & 1ull) xv = -1e9f;
          sv[jb] = xv;
        }
        float mx = fmaxf(fmaxf(sv[0], sv[1]), fmaxf(sv[2], sv[3]));
        #pragma unroll
        for (int d = 1; d < 16; d <<= 1)
          mx = fmaxf(mx, __shfl_xor(mx, d, 64));
        const float mnew = fmaxf(m_[i][r], mx);
        const float corr = __expf(m_[i][r] - mnew);
        m_[i][r] = mnew;
        float ps = 0.f;
        const int swp = (prow & 7) << 3;
        #pragma unroll
        for (int jb = 0; jb < 4; ++jb){
          const float p = __expf(sv[jb] - mnew);
          ps += p;
          pbuf[w][prow*64 + ((jb*16 + l15) ^ swp)] = f2bf(p);
        }
        #pragma unroll
        for (int d = 1; d < 16; d <<= 1)
          ps += __shfl_xor(ps, d, 64);
        l_[i][r] = l_[i][r] * corr + ps;
        #pragma unroll
        for (int j2 = 0; j2 < 4; ++j2) acc_o[i][j2][r] *= corr;
      }
    }

    bf16x8 vfr[4][2];
    #pragma unroll
    for (int j2 = 0; j2 < 4; ++j2){
      const int dim = j2*16 + l15;
      const int sw = (dim & 7) << 3;
      #pragma unroll
      for (int kc = 0; kc < 2; ++kc)
        vfr[j2][kc] = *(const bf16x8*)&vtbuf[dim*64 + ((kc*32 + l4*8) ^ sw)];
    }
    #pragma unroll
    for (int i = 0; i < 2; ++i){
      const int prow = i*16 + l15;
      const int swp = (prow & 7) << 3;
      bf16x8 pa0 = *(const bf16x8*)&pbuf[w][prow*64 + ((l4*8) ^ swp)];
      bf16x8 pa1 = *(const bf16x8*)&pbuf[w][prow*64 + ((32 + l4*8) ^ swp)];
      #pragma unroll
      for (int j2 = 0; j2 < 4; ++j2){
        acc_o[i][j2] = __builtin_amdgcn_mfma_f32_16x16x32_bf16(pa0, vfr[j2][0], acc_o[i][j2], 0,0,0);
        acc_o[i][j2] = __builtin_amdgcn_mfma_f32_16x16x32_bf16(pa1, vfr[j2][1], acc_o[i][j2], 0,0,0);
      }
    }
  }

  #pragma unroll
  for (int i = 0; i < 2; ++i){
    #pragma unroll
    for (int r = 0; r < 4; ++r){
      const int qrow = qt*128 + w*32 + i*16 + l4*4 + r;
      const float inv = 1.f / l_[i][r];
      const size_t ob = ((size_t)b*256 + qrow)*512 + h*64;
      #pragma unroll
      for (int j2 = 0; j2 < 4; ++j2)
        out[ob + j2*16 + l15] = f2bf(acc_o[i][j2][r] * inv);
    }
  }
}

// -------- fused residual + LayerNorm + npm; a bf16, res f32|bf16, out bf16 ---
template<int RF32>
__global__ __launch_bounds__(256) void ln_fused(
    const u16* a, const void* __restrict__ res,
    const float* __restrict__ sc, const float* __restrict__ bs,
    const float* __restrict__ npm, u16* out)
{
  const int row = blockIdx.x, t = threadIdx.x;
  const size_t bse = (size_t)row * 1024 + t*4;
  u16x4 av = *(const u16x4*)&a[bse];
  float rv[4];
  if (RF32){
    f32x4 q = *(const f32x4*)&((const float*)res)[bse];
    #pragma unroll
    for (int j = 0; j < 4; ++j) rv[j] = q[j];
  } else {
    u16x4 q = *(const u16x4*)&((const u16*)res)[bse];
    #pragma unroll
    for (int j = 0; j < 4; ++j) rv[j] = bf2f(q[j]);
  }
  float vv[4]; float s = 0.f, sq = 0.f;
  #pragma unroll
  for (int j = 0; j < 4; ++j){
    vv[j] = bf2f(av[j]) + rv[j];
    s += vv[j]; sq += vv[j]*vv[j];
  }
  #pragma unroll
  for (int i = 1; i < 64; i <<= 1){
    s  += __shfl_xor(s,  i, 64);
    sq += __shfl_xor(sq, i, 64);
  }
  __shared__ float red[8];
  const int wid = t >> 6, lane = t & 63;
  if (lane == 0){ red[wid] = s; red[4 + wid] = sq; }
  __syncthreads();
  s  = red[0] + red[1] + red[2] + red[3];
  sq = red[4] + red[5] + red[6] + red[7];
  const float mean = s * (1.f/1024.f);
  const float var  = sq * (1.f/1024.f) - mean*mean;
  const float rstd = rsqrtf(var + 1e-5f);
  const float nm   = npm[row];
  u16x4 ov;
  #pragma unroll
  for (int j = 0; j < 4; ++j){
    float y = (vv[j] - mean) * rstd * sc[t*4+j] + bs[t*4+j];
    ov[j] = f2bf(y * nm);
  }
  *(u16x4*)&out[bse] = ov;
}

// ---------------- launcher ---------------------------------------------------
extern "C" void kernel_launch(void* const* d_in, const int* in_sizes, int n_in,
                              void* d_out, int out_size, void* d_ws, size_t ws_size,
                              hipStream_t stream)
{
  // ws (u16 el), 112 MiB (proven):
  //  W  [0, 8388608): wqkvT|woT|w1T|w2T|fcT
  //  R1 [8388608, 25165824):  xbf (phase1) -> tmp -> xl (phase2, in-place LN)
  //  R2 [25165824, 41943040): qkvh [8192][1536] (phase1) -> ln1 (phase2)
  //  R3 [41943040, 58720256): xg  (written once, layer-0 end; nothing aliases)
  // d_out (u16): attnb0 [0,8388608) | attnb1 [8388608,16777216)
  //   phase1: mb_g/mb_l @ 16777216 | phase2: hbufA [16777216,33554432)
  const size_t NEED = 58720256ull * 2ull;
  if (ws_size < NEED){
    zero_out<<<4096, 256, 0, stream>>>((float*)d_out, out_size);
    return;
  }

  const float* x   = (const float*)d_in[0];
  const int*   adj = (const int*)d_in[1];
  const float* npm = (const float*)d_in[2];
  const int*   slf = (const int*)d_in[3];
  const float* fcw = (const float*)d_in[30];
  const float* fcb = (const float*)d_in[31];

  u16* ws    = (u16*)d_ws;
  u16* wqkvT = ws;
  u16* woT   = ws + 1572864;
  u16* w1T   = ws + 2097152;
  u16* w2T   = ws + 4194304;
  u16* fcT   = ws + 6291456;
  u16* xbf   = ws + 8388608;           // R1: [16384][1024] bf16, then tmp/xl
  u16* tmp   = ws + 8388608;
  u16* qkvh  = ws + 25165824;          // R2: [8192][1536], then ln1
  u16* ln1   = ws + 25165824;
  u16* xg    = ws + 41943040;          // R3 (exclusive)

  u16* dout16 = (u16*)d_out;
  u16* attnb0 = dout16;                // [16384][512]
  u16* attnb1 = dout16 + 8388608;      // [16384][512]
  u16* hbufA  = dout16 + 16777216;     // [16384][1024] (phase2 only)
  u64* mb_g   = (u64*)(dout16 + 16777216);   // phase1 only (hbufA window)
  u64* mb_l   = mb_g + 65536;

  cvt_bf16<<<8192, 256, 0, stream>>>(x, xbf);
  mask_pack<<<16384, 256, 0, stream>>>(slf, adj, mb_g, mb_l);
  transpose_w<<<dim3(64, 32), 256, 0, stream>>>(fcw, fcT, 2048, 1024, 0);

  // Phase 1: both layers' QKV + attention (xbf + masks live throughout)
  for (int L = 0; L < 2; ++L){
    const int bi = 4 + L*13;
    transpose_w<<<dim3(32, 16), 256, 0, stream>>>((const float*)d_in[bi+0], wqkvT, 1024, 512, 0);
    transpose_w<<<dim3(32, 16), 256, 0, stream>>>((const float*)d_in[bi+1], wqkvT, 1024, 512, 512);
    transpose_w<<<dim3(32, 16), 256, 0, stream>>>((const float*)d_in[bi+2], wqkvT, 1024, 512, 1024);
    u16* attnb = L ? attnb1 : attnb0;
    for (int hf = 0; hf < 2; ++hf){
      const u16* xh = xbf + (size_t)hf*8192*1024;
      gemm256<0,0,0><<<dim3(32, 6), 512, 0, stream>>>(
          xh, xh, 1024, 1024, wqkvT, 1024, 8192, 1536, 1024, nullptr, qkvh, 1536);
      attn_mfma<<<512, 256, 0, stream>>>(qkvh, L ? mb_l : mb_g, hf*32, attnb);
    }
  }

  // Phase 2: layer bodies (xbf/masks dead; tmp R1, ln1 R2, hbufA in d_out)
  for (int L = 0; L < 2; ++L){
    const int bi = 4 + L*13;
    const float* bo  = (const float*)d_in[bi+4];
    const float* l1s = (const float*)d_in[bi+5];
    const float* l1b = (const float*)d_in[bi+6];
    const float* b1  = (const float*)d_in[bi+8];
    const float* b2  = (const float*)d_in[bi+10];
    const float* l2s = (const float*)d_in[bi+11];
    const float* l2b = (const float*)d_in[bi+12];

    transpose_w<<<dim3(16, 32), 256, 0, stream>>>((const float*)d_in[bi+3], woT, 512, 1024, 0);
    transpose_w<<<dim3(32, 64), 256, 0, stream>>>((const float*)d_in[bi+7], w1T, 1024, 2048, 0);
    transpose_w<<<dim3(64, 32), 256, 0, stream>>>((const float*)d_in[bi+9], w2T, 2048, 1024, 0);

    const u16* attnb = L ? attnb1 : attnb0;
    // out-proj + bo -> tmp
    gemm256<0,0,0><<<dim3(64, 4), 512, 0, stream>>>(
        attnb, attnb, 512, 512, woT, 512, 16384, 1024, 512, bo, tmp, 1024);
    // ln1 = LN(tmp + x) * npm -> R2
    ln_fused<1><<<16384, 256, 0, stream>>>(tmp, x, l1s, l1b, npm, ln1);
    // FFN: two N-halves of w1 through hbufA, K-accumulated into tmp
    for (int hh = 0; hh < 2; ++hh){
      gemm256<1,0,0><<<dim3(64, 4), 512, 0, stream>>>(
          ln1, ln1, 1024, 1024, w1T + (size_t)hh*1024*1024, 1024,
          16384, 1024, 1024, b1 + hh*1024, hbufA, 1024);
      if (hh == 0)
        gemm256<0,0,0><<<dim3(64, 4), 512, 0, stream>>>(
            hbufA, hbufA, 1024, 1024, w2T, 2048, 16384, 1024, 1024, b2, tmp, 1024);
      else
        gemm256<0,0,1><<<dim3(64, 4), 512, 0, stream>>>(
            hbufA, hbufA, 1024, 1024, w2T + 1024, 2048, 16384, 1024, 1024,
            nullptr, tmp, 1024);
    }
    // xout = LN(tmp + ln1) * npm; layer0 -> xg, layer1 -> in-place (xl = tmp)
    ln_fused<0><<<16384, 256, 0, stream>>>(tmp, ln1, l2s, l2b, npm, L ? tmp : xg);
  }

  // final: [xg | xl] @ fcT + fc_b -> d_out (f32), K split at 1024
  gemm256<0,1,0><<<dim3(64, 4), 512, 0, stream>>>(
      xg, tmp, 1024, 1024, fcT, 2048, 16384, 1024, 2048, fcb, d_out, 1024);
}